// Round 13
// baseline (1445.690 us; speedup 1.0000x reference)
//
#include <hip/hip_runtime.h>
#include <math.h>

// Per-sample fully-fused iterated CNN. Persistent blocks, 256 threads, atomic
// work-stealing, 3 blocks/CU, FULL fp32 (r3/r4: mantissa compression is
// chaotically amplified over 9 iterations -> fails). VGPR pinned by COUNT.
// 12-round pattern: inst-count cuts win (r7/r11/r12), inst-count adds lose
// (r9/r10), scheduling-only changes flat (r6/r8) -> kernel is ISSUE-bound.
// This round: kill the two largest remaining inst blocks via a one-time PREP
// kernel into d_ws (stream-ordered, graph-safe):
//  (1) c_wl transposed to WT[169][1296] -> fc c-pass reads its own contiguous
//      row as float4: 324 loads vs 1296 (same FMA order -> bit-identical);
//  (2) c_w2/c_w1 rows padded 25->32 floats (128B-aligned) -> wreg fill =
//      6 x dwordx4 + 1 vs 25 scalars (conv2: 400->112 loads/thread/pass).
// Fallback if ws_size < ~0.9MB: counter at ws[0], original load paths.
#define RP40S 44   // (-1)-padded 40x44 state (16B-aligned rows)
#define H1W   31   // h1 col stride: 2 left pads + 28 + 1 right pad (zeros)

// d_ws float-offsets
#define WS_WLT    0        // 169*1296 transposed c_wl
#define WS_W2P    219024   // 128*32 padded c_w2
#define WS_W1P    223120   // 8*32 padded c_w1
#define WS_CNT    223376   // work-stealing counter (int)
#define WS_FLOATS 223377

struct SharedBufs {
    float rp40[2][40*RP40S]; // 14080 B  (state, -1 pads, double-buffered)
    float h1p[8*28*H1W];     // 27776 B  (conv1 activations, fp32, zero col-pads)
    float pbuf[1296];        //  5184 B  (pooled feats -> fc input, 16B-aligned)
    float wker[13*16];       //   832 B  (13x13 kernel, rows padded to 16)
    float num_s[10];         //    40 B
    int   next;              //     4 B  (work-stealing broadcast slot)
};                           // 47916 B -> 48128 block -> 3 blocks/CU

__global__ void prep_ws(const float* __restrict__ c_wl,
                        const float* __restrict__ c_w2,
                        const float* __restrict__ c_w1,
                        float* __restrict__ ws)
{
    const int t = blockIdx.x*256 + threadIdx.x;
    for (int idx = t; idx < 1296*169; idx += gridDim.x*256) {
        const int i = idx / 169, o = idx % 169;
        ws[WS_WLT + o*1296 + i] = c_wl[idx];       // WT[o][i] = W[i][o]
    }
    if (t < 128*25) ws[WS_W2P + (t/25)*32 + (t%25)] = c_w2[t];
    if (t < 8*25)   ws[WS_W1P + (t/25)*32 + (t%25)] = c_w1[t];
}

template<int OUT, bool PAD>
__device__ __forceinline__ void fc_tanh(const float* __restrict__ Wg,
                                        const float* __restrict__ bg,
                                        const float* __restrict__ p,
                                        float* __restrict__ dst, int tid)
{
    if (tid < OUT) {
        float a[8];
        #pragma unroll
        for (int u = 0; u < 8; ++u) a[u] = 0.f;
        #pragma unroll 8
        for (int i0 = 0; i0 < 1296; i0 += 8) {
            const float4 p0 = *(const float4*)&p[i0];
            const float4 p1 = *(const float4*)&p[i0+4];
            a[0] = fmaf(p0.x, Wg[(i0+0)*OUT + tid], a[0]);
            a[1] = fmaf(p0.y, Wg[(i0+1)*OUT + tid], a[1]);
            a[2] = fmaf(p0.z, Wg[(i0+2)*OUT + tid], a[2]);
            a[3] = fmaf(p0.w, Wg[(i0+3)*OUT + tid], a[3]);
            a[4] = fmaf(p1.x, Wg[(i0+4)*OUT + tid], a[4]);
            a[5] = fmaf(p1.y, Wg[(i0+5)*OUT + tid], a[5]);
            a[6] = fmaf(p1.z, Wg[(i0+6)*OUT + tid], a[6]);
            a[7] = fmaf(p1.w, Wg[(i0+7)*OUT + tid], a[7]);
        }
        float s = ((a[0]+a[1])+(a[2]+a[3])) + ((a[4]+a[5])+(a[6]+a[7])) + bg[tid];
        dst[PAD ? (tid/13)*16 + (tid%13) : tid] = tanhf(s);
    }
}

// fc against the TRANSPOSED weight copy: thread tid streams its contiguous
// 1296-float row via float4 (324 loads vs 1296; identical FMA order).
__device__ __forceinline__ void fc_tanh_T169(const float* __restrict__ WT,
                                             const float* __restrict__ bg,
                                             const float* __restrict__ p,
                                             float* __restrict__ dst, int tid)
{
    if (tid < 169) {
        const float* wrow = WT + tid*1296;   // 5184B stride: 16B-aligned
        float a[8];
        #pragma unroll
        for (int u = 0; u < 8; ++u) a[u] = 0.f;
        #pragma unroll 8
        for (int i0 = 0; i0 < 1296; i0 += 8) {
            const float4 p0 = *(const float4*)&p[i0];
            const float4 p1 = *(const float4*)&p[i0+4];
            const float4 w0 = *(const float4*)&wrow[i0];
            const float4 w1 = *(const float4*)&wrow[i0+4];
            a[0] = fmaf(p0.x, w0.x, a[0]);
            a[1] = fmaf(p0.y, w0.y, a[1]);
            a[2] = fmaf(p0.z, w0.z, a[2]);
            a[3] = fmaf(p0.w, w0.w, a[3]);
            a[4] = fmaf(p1.x, w1.x, a[4]);
            a[5] = fmaf(p1.y, w1.y, a[5]);
            a[6] = fmaf(p1.z, w1.z, a[6]);
            a[7] = fmaf(p1.w, w1.w, a[7]);
        }
        float s = ((a[0]+a[1])+(a[2]+a[3])) + ((a[4]+a[5])+(a[6]+a[7])) + bg[tid];
        dst[(tid/13)*16 + (tid%13)] = tanhf(s);
    }
}

// conv1 pad-correction constants (validated algebra r5-r12): true conv =
// computed-on-(-1)-pads + sum_oob(w); base + 4 edge-column terms, hoisted.
__device__ __forceinline__ void conv1_corr(const float* __restrict__ w1g,
                                           const float* __restrict__ b1g,
                                           int c, int y,
                                           float& base, float& e0, float& e1,
                                           float& e26, float& e27)
{
    float wreg[25];
    #pragma unroll
    for (int t = 0; t < 25; ++t) wreg[t] = w1g[c*25 + t];
    float csR[5];
    float S_all = 0.f, SR = 0.f;
    #pragma unroll
    for (int kx = 0; kx < 5; ++kx) {
        float a = wreg[kx] + wreg[5+kx] + wreg[10+kx] + wreg[15+kx] + wreg[20+kx];
        float ex = 0.f;
        if (y == 0)       ex = wreg[kx] + wreg[5+kx];   // rows ky=0,1 oob
        else if (y == 1)  ex = wreg[kx];                // row ky=0 oob
        if (y == 26)      ex += wreg[20+kx];            // row ky=4 oob
        else if (y == 27) ex += wreg[15+kx] + wreg[20+kx];
        csR[kx] = a - ex;
        S_all += a; SR += csR[kx];
    }
    base = b1g[c] + (S_all - SR);
    e0  = csR[0] + csR[1];
    e1  = csR[0];
    e26 = csR[4];
    e27 = csR[3] + csR[4];
}

// load a 25-float kernel row: padded (32-stride, 128B-aligned, 7 insts) or
// original (25 scalars). pw is wave-uniform.
__device__ __forceinline__ void load_w25(float* wreg, const float* __restrict__ base,
                                         bool pw)
{
    if (pw) {
        const float4* q = (const float4*)base;
        #pragma unroll
        for (int t = 0; t < 6; ++t) {
            float4 v = q[t];
            wreg[4*t+0]=v.x; wreg[4*t+1]=v.y; wreg[4*t+2]=v.z; wreg[4*t+3]=v.w;
        }
        wreg[24] = base[24];
    } else {
        #pragma unroll
        for (int t = 0; t < 25; ++t) wreg[t] = base[t];
    }
}

// conv2 helpers (r7-proven): static-indexed row load (clamped) + FMA block.
#define C2_LOADROW(dst, YY) {                                                  \
    int rr_ = crow0 + (YY); rr_ = rr_ < 2 ? 2 : (rr_ > 29 ? 29 : rr_);         \
    const float* hp_ = plane + (rr_ - 2)*H1W;                                  \
    _Pragma("unroll") for (int j = 0; j < 13; ++j) dst[j] = hp_[j]; }

#define C2_FMAROW(src, YY)                                                     \
    if ((unsigned)(crow0 + (YY) - 2) <= 27u) {                                 \
      _Pragma("unroll") for (int t = 0; t < 3; ++t) {                          \
        const int ky_ = (YY) - t;                                              \
        if (ky_ >= 0 && ky_ <= 4) {                                            \
          _Pragma("unroll") for (int kx = 0; kx < 5; ++kx) {                   \
            const float w_ = wreg[ky_*5+kx];                                   \
            _Pragma("unroll") for (int u = 0; u < 9; ++u)                      \
              acc[t*9+u] = fmaf(w_, src[u+kx], acc[t*9+u]); } } } }

__device__ __forceinline__ void trunk_pass(SharedBufs& sb,
                                           const float* __restrict__ rpc,
                                           int tid,
                                           const float* __restrict__ w1g,
                                           const float* __restrict__ w2g,
                                           const float* __restrict__ b2g,
                                           bool pw, int wstride,
                                           float base, float e0, float e1,
                                           float e26, float e27)
{
    // ---- conv1 5x5 pad2 + relu -> h1p. thread = (y, c): c=tid&7 so a y-group
    // of 8 lanes broadcasts the same rpc row. Pad correction pre-hoisted.
    if (tid < 224) {
        const int c = tid & 7;
        const int y = tid >> 3;
        float wreg[25];
        load_w25(wreg, w1g + c*wstride, pw);
        float acc[28];
        #pragma unroll
        for (int x = 0; x < 28; ++x) acc[x] = base;
        acc[0]  += e0;
        acc[1]  += e1;
        acc[26] += e26;
        acc[27] += e27;
        #pragma unroll
        for (int ky = 0; ky < 5; ++ky) {
            // state rows y+4..y+8, cols 4..35 (state cols -2..29), 16B-aligned
            const float4* rr = (const float4*)&rpc[(y+4+ky)*RP40S + 4];
            float rv[32];
            #pragma unroll
            for (int q = 0; q < 8; ++q) {
                float4 t = rr[q];
                rv[q*4+0]=t.x; rv[q*4+1]=t.y; rv[q*4+2]=t.z; rv[q*4+3]=t.w;
            }
            #pragma unroll
            for (int kx = 0; kx < 5; ++kx) {
                const float w = wreg[ky*5+kx];
                #pragma unroll
                for (int x = 0; x < 28; ++x) acc[x] = fmaf(w, rv[x+kx], acc[x]);
            }
        }
        float* hp = &sb.h1p[(c*28 + y)*H1W + 2];
        #pragma unroll
        for (int x = 0; x < 28; ++x) hp[x] = fmaxf(acc[x], 0.f);
    }
    __syncthreads();

    // ---- conv2 5x5 pad2 + relu + maxpool3 -> pbuf[1296].
    // 240 threads cover 16c x 5pyg x 3pxg; 2 pooled rows sequentially
    // (acc[27], live ~120 regs). ra/rb ping-pong row prefetch (r7).
    // Weights from padded ws copy when available (7 vs 25 insts per row).
    if (tid < 240) {
        const int c    = tid / 15;
        const int rem  = tid % 15;
        const int pyg  = rem / 3;
        const int pxg  = rem % 3;
        const int col0 = pxg * 9;   // first padded h1 col needed
        const float bias = b2g[c];
        #pragma unroll 1
        for (int h = 0; h < 2; ++h) {
            const int py = pyg*2 + h;
            if (py >= 9) break;            // only pyg==4,h==1
            const int crow0 = py * 3;      // first conv row (=first padded h1 row)
            float acc[27];                 // acc[t*9+u]: conv rows t=0..2, cols u=0..8
            #pragma unroll
            for (int i = 0; i < 27; ++i) acc[i] = bias;
            for (int ic = 0; ic < 8; ++ic) {
                float wreg[25];
                load_w25(wreg, w2g + (c*8+ic)*wstride, pw);
                const float* plane = &sb.h1p[ic*28*H1W + col0];
                float ra[13], rb[13];
                C2_LOADROW(ra, 0)
                C2_LOADROW(rb, 1)  C2_FMAROW(ra, 0)
                C2_LOADROW(ra, 2)  C2_FMAROW(rb, 1)
                C2_LOADROW(rb, 3)  C2_FMAROW(ra, 2)
                C2_LOADROW(ra, 4)  C2_FMAROW(rb, 3)
                C2_LOADROW(rb, 5)  C2_FMAROW(ra, 4)
                C2_LOADROW(ra, 6)  C2_FMAROW(rb, 5)
                                   C2_FMAROW(ra, 6)
            }
            #pragma unroll
            for (int pxi = 0; pxi < 3; ++pxi) {
                float m = acc[pxi*3];
                #pragma unroll
                for (int dy = 0; dy < 3; ++dy)
                    #pragma unroll
                    for (int dx = 0; dx < 3; ++dx)
                        m = fmaxf(m, acc[dy*9 + pxi*3 + dx]);
                sb.pbuf[c*81 + py*9 + pxg*3 + pxi] = fmaxf(m, 0.f);
            }
        }
    }
    __syncthreads();
}

__device__ __forceinline__ void depthwise13_regs(SharedBufs& sb,
                                                 const float* __restrict__ rpc,
                                                 int y, int x0,
                                                 float& a0, float& a1,
                                                 float& a2, float& a3)
{
    // out(y,x) = sum wker[ky][kx] * rpc[y+ky][x+kx]; wker rows padded to 16
    // -> 4 x ds_read_b128 per row. Results stay in registers; caller writes
    // into the OTHER state buffer (no WAR).
    a0=0.f; a1=0.f; a2=0.f; a3=0.f;
    #pragma unroll 1
    for (int ky = 0; ky < 13; ++ky) {
        const float4* rr = (const float4*)&rpc[(y+ky)*RP40S + x0];
        float rv[16];
        #pragma unroll
        for (int q = 0; q < 4; ++q) {
            float4 t = rr[q];
            rv[q*4+0]=t.x; rv[q*4+1]=t.y; rv[q*4+2]=t.z; rv[q*4+3]=t.w;
        }
        const float4* wq = (const float4*)&sb.wker[ky*16];
        float wv[16];
        #pragma unroll
        for (int q = 0; q < 4; ++q) {
            float4 t = wq[q];
            wv[q*4+0]=t.x; wv[q*4+1]=t.y; wv[q*4+2]=t.z; wv[q*4+3]=t.w;
        }
        #pragma unroll
        for (int kx = 0; kx < 13; ++kx) {
            const float w = wv[kx];
            a0 = fmaf(w, rv[kx+0], a0);
            a1 = fmaf(w, rv[kx+1], a1);
            a2 = fmaf(w, rv[kx+2], a2);
            a3 = fmaf(w, rv[kx+3], a3);
        }
    }
}

__global__ __launch_bounds__(256) __attribute__((amdgpu_num_vgpr(168)))
void modeld_fused(const float* __restrict__ x,
                  const float* __restrict__ n_w1, const float* __restrict__ n_b1,
                  const float* __restrict__ n_w2, const float* __restrict__ n_b2,
                  const float* __restrict__ n_wl, const float* __restrict__ n_bl,
                  const float* __restrict__ c_w1, const float* __restrict__ c_b1,
                  const float* __restrict__ c_w2, const float* __restrict__ c_b2,
                  const float* __restrict__ c_wl, const float* __restrict__ c_bl,
                  float* __restrict__ out,
                  const float* __restrict__ wsb, int use_ws,
                  int* __restrict__ counter, int B)
{
    __shared__ SharedBufs sb;
    const int tid = threadIdx.x;
    const int dy  = tid / 7;          // dw/state mapping: thread<196 owns
    const int dx0 = (tid % 7) * 4;    // outputs (dy, dx0..dx0+3)

    // c-pass weight sources (padded ws copies when available)
    const float* cw1 = use_ws ? wsb + WS_W1P : c_w1;
    const float* cw2 = use_ws ? wsb + WS_W2P : c_w2;
    const int    cws = use_ws ? 32 : 25;

    // hoisted conv1 pad-correction constants (weights fixed for whole kernel)
    float nb=0.f, ne0=0.f, ne1=0.f, ne26=0.f, ne27=0.f;
    float cb=0.f, ce0=0.f, ce1=0.f, ce26=0.f, ce27=0.f;
    if (tid < 224) {
        conv1_corr(n_w1, n_b1, tid & 7, tid >> 3, nb, ne0, ne1, ne26, ne27);
        conv1_corr(c_w1, c_b1, tid & 7, tid >> 3, cb, ce0, ce1, ce26, ce27);
    }

    // one-time pad init for BOTH state buffers (pads persist; only interiors
    // are rewritten) and h1p zero pads.
    for (int i = tid; i < 2*40*RP40S; i += 256) sb.rp40[0][i] = -1.f;
    for (int i = tid; i < 8*28*H1W;   i += 256) sb.h1p[i]  = 0.f;

    while (true) {
        if (tid == 0) sb.next = atomicAdd(counter, 1);
        __syncthreads();                       // also orders pad init / prev sample
        const int b = sb.next;
        if (b >= B) break;                     // uniform exit

        // load x (float4 per dw mapping) into state buf 0; keep in regs
        float cur[4] = {0.f, 0.f, 0.f, 0.f};
        if (tid < 196) {
            const float4 t = *(const float4*)&x[b*784 + dy*28 + dx0];
            cur[0]=t.x; cur[1]=t.y; cur[2]=t.z; cur[3]=t.w;
            float* rp = &sb.rp40[0][(dy+6)*RP40S + dx0 + 6];
            rp[0]=t.x; rp[1]=t.y; rp[2]=t.z; rp[3]=t.w;
        }
        __syncthreads();

        // ---- n-trunk -> num[0..9] (original weight layout; once per sample)
        trunk_pass(sb, sb.rp40[0], tid, n_w1, n_w2, n_b2, false, 25,
                   nb, ne0, ne1, ne26, ne27);
        fc_tanh<10, false>(n_wl, n_bl, sb.pbuf, sb.num_s, tid);
        __syncthreads();

        float o[4];
        {
            const float n0 = sb.num_s[0];
            #pragma unroll
            for (int q = 0; q < 4; ++q) o[q] = n0 * cur[q];
        }

        // ---- 9 iterations, state ping-pongs between rp40[0] and rp40[1]
        int curbuf = 0;
        for (int k = 1; k <= 9; ++k) {
            const float* rpc = sb.rp40[curbuf];
            float*       rpn = sb.rp40[curbuf ^ 1];
            trunk_pass(sb, rpc, tid, cw1, cw2, c_b2, use_ws != 0, cws,
                       cb, ce0, ce1, ce26, ce27);
            if (use_ws) fc_tanh_T169(wsb + WS_WLT, c_bl, sb.pbuf, sb.wker, tid);
            else        fc_tanh<169, true>(c_wl, c_bl, sb.pbuf, sb.wker, tid);
            __syncthreads();
            if (tid < 196) {
                float a0, a1, a2, a3;
                depthwise13_regs(sb, rpc, dy, dx0, a0, a1, a2, a3);
                // write NEW state into the other buffer: no WAR hazard
                const float nk = sb.num_s[k];
                o[0] = fmaf(nk, a0, o[0]);
                o[1] = fmaf(nk, a1, o[1]);
                o[2] = fmaf(nk, a2, o[2]);
                o[3] = fmaf(nk, a3, o[3]);
                float* rp = &rpn[(dy+6)*RP40S + dx0 + 6];
                rp[0]=a0; rp[1]=a1; rp[2]=a2; rp[3]=a3;
            }
            __syncthreads();                   // new state visible to next conv1
            curbuf ^= 1;
        }

        if (tid < 196)
            *(float4*)&out[b*784 + dy*28 + dx0] = make_float4(o[0], o[1], o[2], o[3]);
        // no barrier needed: next iteration's grab+sync orders everything
    }
}

extern "C" void kernel_launch(void* const* d_in, const int* in_sizes, int n_in,
                              void* d_out, int out_size, void* d_ws, size_t ws_size,
                              hipStream_t stream)
{
    const float* x    = (const float*)d_in[0];
    const float* n_w1 = (const float*)d_in[1];
    const float* n_b1 = (const float*)d_in[2];
    const float* n_w2 = (const float*)d_in[3];
    const float* n_b2 = (const float*)d_in[4];
    const float* n_wl = (const float*)d_in[5];
    const float* n_bl = (const float*)d_in[6];
    const float* c_w1 = (const float*)d_in[7];
    const float* c_b1 = (const float*)d_in[8];
    const float* c_w2 = (const float*)d_in[9];
    const float* c_b2 = (const float*)d_in[10];
    const float* c_wl = (const float*)d_in[11];
    const float* c_bl = (const float*)d_in[12];
    float* out = (float*)d_out;

    const int B = in_sizes[0] / 784;
    const int use_ws = (ws_size >= (size_t)WS_FLOATS*4 + 4) ? 1 : 0;
    float* wsb = (float*)d_ws;
    int* counter = use_ws ? (int*)(wsb + WS_CNT) : (int*)d_ws;

    hipMemsetAsync(counter, 0, sizeof(int), stream);
    if (use_ws)
        hipLaunchKernelGGL(prep_ws, dim3(512), dim3(256), 0, stream,
                           c_wl, c_w2, c_w1, wsb);

    const int grid = B < 768 ? B : 768;             // 3 blocks/CU x 256 CUs
    hipLaunchKernelGGL(modeld_fused, dim3(grid), dim3(256), 0, stream,
                       x, n_w1, n_b1, n_w2, n_b2, n_wl, n_bl,
                       c_w1, c_b1, c_w2, c_b2, c_wl, c_bl, out,
                       wsb, use_ws, counter, B);
}

// Round 14
// 1330.625 us; speedup vs baseline: 1.0865x; 1.0865x over previous
//
#include <hip/hip_runtime.h>
#include <math.h>

// Per-sample fully-fused iterated CNN. Persistent blocks, 256 threads, atomic
// work-stealing, 3 blocks/CU, FULL fp32 (r3/r4: mantissa compression is
// chaotically amplified over 9 iterations -> fails). VGPR pinned by COUNT.
// Pattern: inst-count cuts win (r7/r11/r12) UNLESS they raise memory
// transactions (r13: fc transpose = 64 cache lines/load vs 2 coalesced ->
// regressed); scheduling-only changes flat (r6/r8).
// This round = r12 (1299us best) + the one clean r13 piece: c_w2/c_w1 rows
// padded 25->32 floats in d_ws (prep kernel, stream-ordered). These loads are
// wave-BROADCAST (15 lanes share c -> same address), so padding cuts
// instructions (25 scalar -> 6x dwordx4 +1) with zero transaction change.
// Fallback if ws_size too small: counter at ws[0], original load paths.
#define RP40S 44   // (-1)-padded 40x44 state (16B-aligned rows)
#define H1W   31   // h1 col stride: 2 left pads + 28 + 1 right pad (zeros)

// d_ws float-offsets
#define WS_W2P    0        // 128*32 padded c_w2
#define WS_W1P    4096     // 8*32 padded c_w1
#define WS_CNT    4352     // work-stealing counter (int)
#define WS_FLOATS 4353

struct SharedBufs {
    float rp40[2][40*RP40S]; // 14080 B  (state, -1 pads, double-buffered)
    float h1p[8*28*H1W];     // 27776 B  (conv1 activations, fp32, zero col-pads)
    float pbuf[1296];        //  5184 B  (pooled feats -> fc input, 16B-aligned)
    float wker[13*16];       //   832 B  (13x13 kernel, rows padded to 16)
    float num_s[10];         //    40 B
    int   next;              //     4 B  (work-stealing broadcast slot)
};                           // 47916 B -> 48128 block -> 3 blocks/CU

__global__ void prep_ws(const float* __restrict__ c_w2,
                        const float* __restrict__ c_w1,
                        float* __restrict__ ws)
{
    const int t = blockIdx.x*256 + threadIdx.x;
    if (t < 128*25) ws[WS_W2P + (t/25)*32 + (t%25)] = c_w2[t];
    if (t < 8*25)   ws[WS_W1P + (t/25)*32 + (t%25)] = c_w1[t];
}

template<int OUT, bool PAD>
__device__ __forceinline__ void fc_tanh(const float* __restrict__ Wg,
                                        const float* __restrict__ bg,
                                        const float* __restrict__ p,
                                        float* __restrict__ dst, int tid)
{
    if (tid < OUT) {
        float a[8];
        #pragma unroll
        for (int u = 0; u < 8; ++u) a[u] = 0.f;
        #pragma unroll 8
        for (int i0 = 0; i0 < 1296; i0 += 8) {
            const float4 p0 = *(const float4*)&p[i0];
            const float4 p1 = *(const float4*)&p[i0+4];
            a[0] = fmaf(p0.x, Wg[(i0+0)*OUT + tid], a[0]);
            a[1] = fmaf(p0.y, Wg[(i0+1)*OUT + tid], a[1]);
            a[2] = fmaf(p0.z, Wg[(i0+2)*OUT + tid], a[2]);
            a[3] = fmaf(p0.w, Wg[(i0+3)*OUT + tid], a[3]);
            a[4] = fmaf(p1.x, Wg[(i0+4)*OUT + tid], a[4]);
            a[5] = fmaf(p1.y, Wg[(i0+5)*OUT + tid], a[5]);
            a[6] = fmaf(p1.z, Wg[(i0+6)*OUT + tid], a[6]);
            a[7] = fmaf(p1.w, Wg[(i0+7)*OUT + tid], a[7]);
        }
        float s = ((a[0]+a[1])+(a[2]+a[3])) + ((a[4]+a[5])+(a[6]+a[7])) + bg[tid];
        dst[PAD ? (tid/13)*16 + (tid%13) : tid] = tanhf(s);
    }
}

// conv1 pad-correction constants (validated algebra r5-r12): true conv =
// computed-on-(-1)-pads + sum_oob(w); base + 4 edge-column terms, hoisted.
__device__ __forceinline__ void conv1_corr(const float* __restrict__ w1g,
                                           const float* __restrict__ b1g,
                                           int c, int y,
                                           float& base, float& e0, float& e1,
                                           float& e26, float& e27)
{
    float wreg[25];
    #pragma unroll
    for (int t = 0; t < 25; ++t) wreg[t] = w1g[c*25 + t];
    float csR[5];
    float S_all = 0.f, SR = 0.f;
    #pragma unroll
    for (int kx = 0; kx < 5; ++kx) {
        float a = wreg[kx] + wreg[5+kx] + wreg[10+kx] + wreg[15+kx] + wreg[20+kx];
        float ex = 0.f;
        if (y == 0)       ex = wreg[kx] + wreg[5+kx];   // rows ky=0,1 oob
        else if (y == 1)  ex = wreg[kx];                // row ky=0 oob
        if (y == 26)      ex += wreg[20+kx];            // row ky=4 oob
        else if (y == 27) ex += wreg[15+kx] + wreg[20+kx];
        csR[kx] = a - ex;
        S_all += a; SR += csR[kx];
    }
    base = b1g[c] + (S_all - SR);
    e0  = csR[0] + csR[1];
    e1  = csR[0];
    e26 = csR[4];
    e27 = csR[3] + csR[4];
}

// load a 25-float kernel row: padded (32-stride, 128B-aligned, 7 insts) or
// original (25 scalars). pw is wave-uniform; addresses are wave-broadcast.
__device__ __forceinline__ void load_w25(float* wreg, const float* __restrict__ base,
                                         bool pw)
{
    if (pw) {
        const float4* q = (const float4*)base;
        #pragma unroll
        for (int t = 0; t < 6; ++t) {
            float4 v = q[t];
            wreg[4*t+0]=v.x; wreg[4*t+1]=v.y; wreg[4*t+2]=v.z; wreg[4*t+3]=v.w;
        }
        wreg[24] = base[24];
    } else {
        #pragma unroll
        for (int t = 0; t < 25; ++t) wreg[t] = base[t];
    }
}

// conv2 helpers (r7-proven): static-indexed row load (clamped) + FMA block.
#define C2_LOADROW(dst, YY) {                                                  \
    int rr_ = crow0 + (YY); rr_ = rr_ < 2 ? 2 : (rr_ > 29 ? 29 : rr_);         \
    const float* hp_ = plane + (rr_ - 2)*H1W;                                  \
    _Pragma("unroll") for (int j = 0; j < 13; ++j) dst[j] = hp_[j]; }

#define C2_FMAROW(src, YY)                                                     \
    if ((unsigned)(crow0 + (YY) - 2) <= 27u) {                                 \
      _Pragma("unroll") for (int t = 0; t < 3; ++t) {                          \
        const int ky_ = (YY) - t;                                              \
        if (ky_ >= 0 && ky_ <= 4) {                                            \
          _Pragma("unroll") for (int kx = 0; kx < 5; ++kx) {                   \
            const float w_ = wreg[ky_*5+kx];                                   \
            _Pragma("unroll") for (int u = 0; u < 9; ++u)                      \
              acc[t*9+u] = fmaf(w_, src[u+kx], acc[t*9+u]); } } } }

__device__ __forceinline__ void trunk_pass(SharedBufs& sb,
                                           const float* __restrict__ rpc,
                                           int tid,
                                           const float* __restrict__ w1g,
                                           const float* __restrict__ w2g,
                                           const float* __restrict__ b2g,
                                           bool pw, int wstride,
                                           float base, float e0, float e1,
                                           float e26, float e27)
{
    // ---- conv1 5x5 pad2 + relu -> h1p. thread = (y, c): c=tid&7 so a y-group
    // of 8 lanes broadcasts the same rpc row. Pad correction pre-hoisted.
    if (tid < 224) {
        const int c = tid & 7;
        const int y = tid >> 3;
        float wreg[25];
        load_w25(wreg, w1g + c*wstride, pw);
        float acc[28];
        #pragma unroll
        for (int x = 0; x < 28; ++x) acc[x] = base;
        acc[0]  += e0;
        acc[1]  += e1;
        acc[26] += e26;
        acc[27] += e27;
        #pragma unroll
        for (int ky = 0; ky < 5; ++ky) {
            // state rows y+4..y+8, cols 4..35 (state cols -2..29), 16B-aligned
            const float4* rr = (const float4*)&rpc[(y+4+ky)*RP40S + 4];
            float rv[32];
            #pragma unroll
            for (int q = 0; q < 8; ++q) {
                float4 t = rr[q];
                rv[q*4+0]=t.x; rv[q*4+1]=t.y; rv[q*4+2]=t.z; rv[q*4+3]=t.w;
            }
            #pragma unroll
            for (int kx = 0; kx < 5; ++kx) {
                const float w = wreg[ky*5+kx];
                #pragma unroll
                for (int x = 0; x < 28; ++x) acc[x] = fmaf(w, rv[x+kx], acc[x]);
            }
        }
        float* hp = &sb.h1p[(c*28 + y)*H1W + 2];
        #pragma unroll
        for (int x = 0; x < 28; ++x) hp[x] = fmaxf(acc[x], 0.f);
    }
    __syncthreads();

    // ---- conv2 5x5 pad2 + relu + maxpool3 -> pbuf[1296].
    // 240 threads cover 16c x 5pyg x 3pxg; 2 pooled rows sequentially
    // (acc[27], live ~120 regs). ra/rb ping-pong row prefetch (r7).
    // Weights from padded ws copy when available (7 vs 25 insts per row).
    if (tid < 240) {
        const int c    = tid / 15;
        const int rem  = tid % 15;
        const int pyg  = rem / 3;
        const int pxg  = rem % 3;
        const int col0 = pxg * 9;   // first padded h1 col needed
        const float bias = b2g[c];
        #pragma unroll 1
        for (int h = 0; h < 2; ++h) {
            const int py = pyg*2 + h;
            if (py >= 9) break;            // only pyg==4,h==1
            const int crow0 = py * 3;      // first conv row (=first padded h1 row)
            float acc[27];                 // acc[t*9+u]: conv rows t=0..2, cols u=0..8
            #pragma unroll
            for (int i = 0; i < 27; ++i) acc[i] = bias;
            for (int ic = 0; ic < 8; ++ic) {
                float wreg[25];
                load_w25(wreg, w2g + (c*8+ic)*wstride, pw);
                const float* plane = &sb.h1p[ic*28*H1W + col0];
                float ra[13], rb[13];
                C2_LOADROW(ra, 0)
                C2_LOADROW(rb, 1)  C2_FMAROW(ra, 0)
                C2_LOADROW(ra, 2)  C2_FMAROW(rb, 1)
                C2_LOADROW(rb, 3)  C2_FMAROW(ra, 2)
                C2_LOADROW(ra, 4)  C2_FMAROW(rb, 3)
                C2_LOADROW(rb, 5)  C2_FMAROW(ra, 4)
                C2_LOADROW(ra, 6)  C2_FMAROW(rb, 5)
                                   C2_FMAROW(ra, 6)
            }
            #pragma unroll
            for (int pxi = 0; pxi < 3; ++pxi) {
                float m = acc[pxi*3];
                #pragma unroll
                for (int dy = 0; dy < 3; ++dy)
                    #pragma unroll
                    for (int dx = 0; dx < 3; ++dx)
                        m = fmaxf(m, acc[dy*9 + pxi*3 + dx]);
                sb.pbuf[c*81 + py*9 + pxg*3 + pxi] = fmaxf(m, 0.f);
            }
        }
    }
    __syncthreads();
}

__device__ __forceinline__ void depthwise13_regs(SharedBufs& sb,
                                                 const float* __restrict__ rpc,
                                                 int y, int x0,
                                                 float& a0, float& a1,
                                                 float& a2, float& a3)
{
    // out(y,x) = sum wker[ky][kx] * rpc[y+ky][x+kx]; wker rows padded to 16
    // -> 4 x ds_read_b128 per row. Results stay in registers; caller writes
    // into the OTHER state buffer (no WAR).
    a0=0.f; a1=0.f; a2=0.f; a3=0.f;
    #pragma unroll 1
    for (int ky = 0; ky < 13; ++ky) {
        const float4* rr = (const float4*)&rpc[(y+ky)*RP40S + x0];
        float rv[16];
        #pragma unroll
        for (int q = 0; q < 4; ++q) {
            float4 t = rr[q];
            rv[q*4+0]=t.x; rv[q*4+1]=t.y; rv[q*4+2]=t.z; rv[q*4+3]=t.w;
        }
        const float4* wq = (const float4*)&sb.wker[ky*16];
        float wv[16];
        #pragma unroll
        for (int q = 0; q < 4; ++q) {
            float4 t = wq[q];
            wv[q*4+0]=t.x; wv[q*4+1]=t.y; wv[q*4+2]=t.z; wv[q*4+3]=t.w;
        }
        #pragma unroll
        for (int kx = 0; kx < 13; ++kx) {
            const float w = wv[kx];
            a0 = fmaf(w, rv[kx+0], a0);
            a1 = fmaf(w, rv[kx+1], a1);
            a2 = fmaf(w, rv[kx+2], a2);
            a3 = fmaf(w, rv[kx+3], a3);
        }
    }
}

__global__ __launch_bounds__(256) __attribute__((amdgpu_num_vgpr(168)))
void modeld_fused(const float* __restrict__ x,
                  const float* __restrict__ n_w1, const float* __restrict__ n_b1,
                  const float* __restrict__ n_w2, const float* __restrict__ n_b2,
                  const float* __restrict__ n_wl, const float* __restrict__ n_bl,
                  const float* __restrict__ c_w1, const float* __restrict__ c_b1,
                  const float* __restrict__ c_w2, const float* __restrict__ c_b2,
                  const float* __restrict__ c_wl, const float* __restrict__ c_bl,
                  float* __restrict__ out,
                  const float* __restrict__ wsb, int use_ws,
                  int* __restrict__ counter, int B)
{
    __shared__ SharedBufs sb;
    const int tid = threadIdx.x;
    const int dy  = tid / 7;          // dw/state mapping: thread<196 owns
    const int dx0 = (tid % 7) * 4;    // outputs (dy, dx0..dx0+3)

    // c-pass weight sources (padded ws copies when available)
    const float* cw1 = use_ws ? wsb + WS_W1P : c_w1;
    const float* cw2 = use_ws ? wsb + WS_W2P : c_w2;
    const int    cws = use_ws ? 32 : 25;

    // hoisted conv1 pad-correction constants (weights fixed for whole kernel)
    float nb=0.f, ne0=0.f, ne1=0.f, ne26=0.f, ne27=0.f;
    float cb=0.f, ce0=0.f, ce1=0.f, ce26=0.f, ce27=0.f;
    if (tid < 224) {
        conv1_corr(n_w1, n_b1, tid & 7, tid >> 3, nb, ne0, ne1, ne26, ne27);
        conv1_corr(c_w1, c_b1, tid & 7, tid >> 3, cb, ce0, ce1, ce26, ce27);
    }

    // one-time pad init for BOTH state buffers (pads persist; only interiors
    // are rewritten) and h1p zero pads.
    for (int i = tid; i < 2*40*RP40S; i += 256) sb.rp40[0][i] = -1.f;
    for (int i = tid; i < 8*28*H1W;   i += 256) sb.h1p[i]  = 0.f;

    while (true) {
        if (tid == 0) sb.next = atomicAdd(counter, 1);
        __syncthreads();                       // also orders pad init / prev sample
        const int b = sb.next;
        if (b >= B) break;                     // uniform exit

        // load x (float4 per dw mapping) into state buf 0; keep in regs
        float cur[4] = {0.f, 0.f, 0.f, 0.f};
        if (tid < 196) {
            const float4 t = *(const float4*)&x[b*784 + dy*28 + dx0];
            cur[0]=t.x; cur[1]=t.y; cur[2]=t.z; cur[3]=t.w;
            float* rp = &sb.rp40[0][(dy+6)*RP40S + dx0 + 6];
            rp[0]=t.x; rp[1]=t.y; rp[2]=t.z; rp[3]=t.w;
        }
        __syncthreads();

        // ---- n-trunk -> num[0..9] (original weight layout; once per sample)
        trunk_pass(sb, sb.rp40[0], tid, n_w1, n_w2, n_b2, false, 25,
                   nb, ne0, ne1, ne26, ne27);
        fc_tanh<10, false>(n_wl, n_bl, sb.pbuf, sb.num_s, tid);
        __syncthreads();

        float o[4];
        {
            const float n0 = sb.num_s[0];
            #pragma unroll
            for (int q = 0; q < 4; ++q) o[q] = n0 * cur[q];
        }

        // ---- 9 iterations, state ping-pongs between rp40[0] and rp40[1]
        int curbuf = 0;
        for (int k = 1; k <= 9; ++k) {
            const float* rpc = sb.rp40[curbuf];
            float*       rpn = sb.rp40[curbuf ^ 1];
            trunk_pass(sb, rpc, tid, cw1, cw2, c_b2, use_ws != 0, cws,
                       cb, ce0, ce1, ce26, ce27);
            fc_tanh<169, true>(c_wl, c_bl, sb.pbuf, sb.wker, tid);  // coalesced
            __syncthreads();
            if (tid < 196) {
                float a0, a1, a2, a3;
                depthwise13_regs(sb, rpc, dy, dx0, a0, a1, a2, a3);
                // write NEW state into the other buffer: no WAR hazard
                const float nk = sb.num_s[k];
                o[0] = fmaf(nk, a0, o[0]);
                o[1] = fmaf(nk, a1, o[1]);
                o[2] = fmaf(nk, a2, o[2]);
                o[3] = fmaf(nk, a3, o[3]);
                float* rp = &rpn[(dy+6)*RP40S + dx0 + 6];
                rp[0]=a0; rp[1]=a1; rp[2]=a2; rp[3]=a3;
            }
            __syncthreads();                   // new state visible to next conv1
            curbuf ^= 1;
        }

        if (tid < 196)
            *(float4*)&out[b*784 + dy*28 + dx0] = make_float4(o[0], o[1], o[2], o[3]);
        // no barrier needed: next iteration's grab+sync orders everything
    }
}

extern "C" void kernel_launch(void* const* d_in, const int* in_sizes, int n_in,
                              void* d_out, int out_size, void* d_ws, size_t ws_size,
                              hipStream_t stream)
{
    const float* x    = (const float*)d_in[0];
    const float* n_w1 = (const float*)d_in[1];
    const float* n_b1 = (const float*)d_in[2];
    const float* n_w2 = (const float*)d_in[3];
    const float* n_b2 = (const float*)d_in[4];
    const float* n_wl = (const float*)d_in[5];
    const float* n_bl = (const float*)d_in[6];
    const float* c_w1 = (const float*)d_in[7];
    const float* c_b1 = (const float*)d_in[8];
    const float* c_w2 = (const float*)d_in[9];
    const float* c_b2 = (const float*)d_in[10];
    const float* c_wl = (const float*)d_in[11];
    const float* c_bl = (const float*)d_in[12];
    float* out = (float*)d_out;

    const int B = in_sizes[0] / 784;
    const int use_ws = (ws_size >= (size_t)WS_FLOATS*4 + 4) ? 1 : 0;
    float* wsb = (float*)d_ws;
    int* counter = use_ws ? (int*)(wsb + WS_CNT) : (int*)d_ws;

    hipMemsetAsync(counter, 0, sizeof(int), stream);
    if (use_ws)
        hipLaunchKernelGGL(prep_ws, dim3(16), dim3(256), 0, stream,
                           c_w2, c_w1, wsb);

    const int grid = B < 768 ? B : 768;             // 3 blocks/CU x 256 CUs
    hipLaunchKernelGGL(modeld_fused, dim3(grid), dim3(256), 0, stream,
                       x, n_w1, n_b1, n_w2, n_b2, n_wl, n_bl,
                       c_w1, c_b1, c_w2, c_b2, c_wl, c_bl, out,
                       wsb, use_ws, counter, B);
}

// Round 15
// 1303.740 us; speedup vs baseline: 1.1089x; 1.0206x over previous
//
#include <hip/hip_runtime.h>
#include <math.h>

// FINAL (r12 revert): Per-sample fully-fused iterated CNN. Persistent blocks,
// 256 threads, atomic work-stealing, 3 blocks/CU, FULL fp32 (r3/r4: mantissa
// compression chaotically amplified over 9 iterations -> fails). VGPR pinned
// by COUNT (amdgpu_num_vgpr; wave-based hints deliver 2x requested waves ->
// catastrophic spill, r1/r5).
// 14-round ledger: inst-count cuts won (r7 +3%, r11 dbuf+fc4, r12 bundle)
// UNLESS they raised memory transactions (r13 fc-transpose: 64 lines/load vs
// 2 coalesced) or codegen bloat (r14 dual-path weight loads: +20 VGPR,
// broadcast scalars -> VMEM). Scheduling-only flat (r6 occupancy, r8 stagger).
// r12 kernel = best verified 1299us: r11 base + (1) wker padded 13x16 -> dw
// reads 4 x ds_read_b128/row; (2) conv1 pad-correction hoisted to kernel
// start; (3) fc unroll 8 + float4 pbuf reads.
#define RP40S 44   // (-1)-padded 40x44 state (16B-aligned rows)
#define H1W   31   // h1 col stride: 2 left pads + 28 + 1 right pad (zeros)

struct SharedBufs {
    float rp40[2][40*RP40S]; // 14080 B  (state, -1 pads, double-buffered)
    float h1p[8*28*H1W];     // 27776 B  (conv1 activations, fp32, zero col-pads)
    float pbuf[1296];        //  5184 B  (pooled feats -> fc input, 16B-aligned)
    float wker[13*16];       //   832 B  (13x13 kernel, rows padded to 16)
    float num_s[10];         //    40 B
    int   next;              //     4 B  (work-stealing broadcast slot)
};                           // 47916 B -> 48128 block -> 3 blocks/CU

template<int OUT, bool PAD>
__device__ __forceinline__ void fc_tanh(const float* __restrict__ Wg,
                                        const float* __restrict__ bg,
                                        const float* __restrict__ p,
                                        float* __restrict__ dst, int tid)
{
    if (tid < OUT) {
        float a[8];
        #pragma unroll
        for (int u = 0; u < 8; ++u) a[u] = 0.f;
        #pragma unroll 8
        for (int i0 = 0; i0 < 1296; i0 += 8) {
            const float4 p0 = *(const float4*)&p[i0];
            const float4 p1 = *(const float4*)&p[i0+4];
            a[0] = fmaf(p0.x, Wg[(i0+0)*OUT + tid], a[0]);
            a[1] = fmaf(p0.y, Wg[(i0+1)*OUT + tid], a[1]);
            a[2] = fmaf(p0.z, Wg[(i0+2)*OUT + tid], a[2]);
            a[3] = fmaf(p0.w, Wg[(i0+3)*OUT + tid], a[3]);
            a[4] = fmaf(p1.x, Wg[(i0+4)*OUT + tid], a[4]);
            a[5] = fmaf(p1.y, Wg[(i0+5)*OUT + tid], a[5]);
            a[6] = fmaf(p1.z, Wg[(i0+6)*OUT + tid], a[6]);
            a[7] = fmaf(p1.w, Wg[(i0+7)*OUT + tid], a[7]);
        }
        float s = ((a[0]+a[1])+(a[2]+a[3])) + ((a[4]+a[5])+(a[6]+a[7])) + bg[tid];
        dst[PAD ? (tid/13)*16 + (tid%13) : tid] = tanhf(s);
    }
}

// conv1 pad-correction constants (per thread, per weight set): true conv =
// computed-on-(-1)-pads + sum_oob(w); decomposed into a base (bias + rows-oob
// term, all x) and 4 edge-column terms. Depends only on (c, y, weights) ->
// hoisted to kernel start (validated algebra r5-r12).
__device__ __forceinline__ void conv1_corr(const float* __restrict__ w1g,
                                           const float* __restrict__ b1g,
                                           int c, int y,
                                           float& base, float& e0, float& e1,
                                           float& e26, float& e27)
{
    float wreg[25];
    #pragma unroll
    for (int t = 0; t < 25; ++t) wreg[t] = w1g[c*25 + t];
    float csR[5];
    float S_all = 0.f, SR = 0.f;
    #pragma unroll
    for (int kx = 0; kx < 5; ++kx) {
        float a = wreg[kx] + wreg[5+kx] + wreg[10+kx] + wreg[15+kx] + wreg[20+kx];
        float ex = 0.f;
        if (y == 0)       ex = wreg[kx] + wreg[5+kx];   // rows ky=0,1 oob
        else if (y == 1)  ex = wreg[kx];                // row ky=0 oob
        if (y == 26)      ex += wreg[20+kx];            // row ky=4 oob
        else if (y == 27) ex += wreg[15+kx] + wreg[20+kx];
        csR[kx] = a - ex;
        S_all += a; SR += csR[kx];
    }
    base = b1g[c] + (S_all - SR);
    e0  = csR[0] + csR[1];
    e1  = csR[0];
    e26 = csR[4];
    e27 = csR[3] + csR[4];
}

// conv2 helpers (r7-proven): static-indexed row load (clamped, always safe)
// and FMA block.
#define C2_LOADROW(dst, YY) {                                                  \
    int rr_ = crow0 + (YY); rr_ = rr_ < 2 ? 2 : (rr_ > 29 ? 29 : rr_);         \
    const float* hp_ = plane + (rr_ - 2)*H1W;                                  \
    _Pragma("unroll") for (int j = 0; j < 13; ++j) dst[j] = hp_[j]; }

#define C2_FMAROW(src, YY)                                                     \
    if ((unsigned)(crow0 + (YY) - 2) <= 27u) {                                 \
      _Pragma("unroll") for (int t = 0; t < 3; ++t) {                          \
        const int ky_ = (YY) - t;                                              \
        if (ky_ >= 0 && ky_ <= 4) {                                            \
          _Pragma("unroll") for (int kx = 0; kx < 5; ++kx) {                   \
            const float w_ = wreg[ky_*5+kx];                                   \
            _Pragma("unroll") for (int u = 0; u < 9; ++u)                      \
              acc[t*9+u] = fmaf(w_, src[u+kx], acc[t*9+u]); } } } }

__device__ __forceinline__ void trunk_pass(SharedBufs& sb,
                                           const float* __restrict__ rpc,
                                           int tid,
                                           const float* __restrict__ w1g,
                                           const float* __restrict__ w2g,
                                           const float* __restrict__ b2g,
                                           float base, float e0, float e1,
                                           float e26, float e27)
{
    // ---- conv1 5x5 pad2 + relu -> h1p. thread = (y, c): c=tid&7 so a y-group
    // of 8 lanes broadcasts the same rpc row. Pad correction pre-hoisted.
    if (tid < 224) {
        const int c = tid & 7;
        const int y = tid >> 3;
        float wreg[25];
        #pragma unroll
        for (int t = 0; t < 25; ++t) wreg[t] = w1g[c*25 + t];
        float acc[28];
        #pragma unroll
        for (int x = 0; x < 28; ++x) acc[x] = base;
        acc[0]  += e0;
        acc[1]  += e1;
        acc[26] += e26;
        acc[27] += e27;
        #pragma unroll
        for (int ky = 0; ky < 5; ++ky) {
            // state rows y+4..y+8, cols 4..35 (state cols -2..29), 16B-aligned
            const float4* rr = (const float4*)&rpc[(y+4+ky)*RP40S + 4];
            float rv[32];
            #pragma unroll
            for (int q = 0; q < 8; ++q) {
                float4 t = rr[q];
                rv[q*4+0]=t.x; rv[q*4+1]=t.y; rv[q*4+2]=t.z; rv[q*4+3]=t.w;
            }
            #pragma unroll
            for (int kx = 0; kx < 5; ++kx) {
                const float w = wreg[ky*5+kx];
                #pragma unroll
                for (int x = 0; x < 28; ++x) acc[x] = fmaf(w, rv[x+kx], acc[x]);
            }
        }
        float* hp = &sb.h1p[(c*28 + y)*H1W + 2];
        #pragma unroll
        for (int x = 0; x < 28; ++x) hp[x] = fmaxf(acc[x], 0.f);
    }
    __syncthreads();

    // ---- conv2 5x5 pad2 + relu + maxpool3 -> pbuf[1296].
    // 240 threads cover 16c x 5pyg x 3pxg; 2 pooled rows sequentially
    // (acc[27], live ~120 regs). ra/rb ping-pong row prefetch (r7).
    // w2/b2 from global (12.8 KB, L1-resident broadcast; 15 lanes share c).
    if (tid < 240) {
        const int c    = tid / 15;
        const int rem  = tid % 15;
        const int pyg  = rem / 3;
        const int pxg  = rem % 3;
        const int col0 = pxg * 9;   // first padded h1 col needed
        const float bias = b2g[c];
        #pragma unroll 1
        for (int h = 0; h < 2; ++h) {
            const int py = pyg*2 + h;
            if (py >= 9) break;            // only pyg==4,h==1
            const int crow0 = py * 3;      // first conv row (=first padded h1 row)
            float acc[27];                 // acc[t*9+u]: conv rows t=0..2, cols u=0..8
            #pragma unroll
            for (int i = 0; i < 27; ++i) acc[i] = bias;
            for (int ic = 0; ic < 8; ++ic) {
                float wreg[25];
                const float* wsrc = &w2g[(c*8+ic)*25];
                #pragma unroll
                for (int t = 0; t < 25; ++t) wreg[t] = wsrc[t];
                const float* plane = &sb.h1p[ic*28*H1W + col0];
                float ra[13], rb[13];
                C2_LOADROW(ra, 0)
                C2_LOADROW(rb, 1)  C2_FMAROW(ra, 0)
                C2_LOADROW(ra, 2)  C2_FMAROW(rb, 1)
                C2_LOADROW(rb, 3)  C2_FMAROW(ra, 2)
                C2_LOADROW(ra, 4)  C2_FMAROW(rb, 3)
                C2_LOADROW(rb, 5)  C2_FMAROW(ra, 4)
                C2_LOADROW(ra, 6)  C2_FMAROW(rb, 5)
                                   C2_FMAROW(ra, 6)
            }
            #pragma unroll
            for (int pxi = 0; pxi < 3; ++pxi) {
                float m = acc[pxi*3];
                #pragma unroll
                for (int dy = 0; dy < 3; ++dy)
                    #pragma unroll
                    for (int dx = 0; dx < 3; ++dx)
                        m = fmaxf(m, acc[dy*9 + pxi*3 + dx]);
                sb.pbuf[c*81 + py*9 + pxg*3 + pxi] = fmaxf(m, 0.f);
            }
        }
    }
    __syncthreads();
}

__device__ __forceinline__ void depthwise13_regs(SharedBufs& sb,
                                                 const float* __restrict__ rpc,
                                                 int y, int x0,
                                                 float& a0, float& a1,
                                                 float& a2, float& a3)
{
    // out(y,x) = sum wker[ky][kx] * rpc[y+ky][x+kx]; wker rows padded to 16
    // -> 4 x ds_read_b128 per row (vs 13 scalar). Results stay in registers;
    // caller writes into the OTHER state buffer (no WAR).
    a0=0.f; a1=0.f; a2=0.f; a3=0.f;
    #pragma unroll 1
    for (int ky = 0; ky < 13; ++ky) {
        const float4* rr = (const float4*)&rpc[(y+ky)*RP40S + x0];
        float rv[16];
        #pragma unroll
        for (int q = 0; q < 4; ++q) {
            float4 t = rr[q];
            rv[q*4+0]=t.x; rv[q*4+1]=t.y; rv[q*4+2]=t.z; rv[q*4+3]=t.w;
        }
        const float4* wq = (const float4*)&sb.wker[ky*16];
        float wv[16];
        #pragma unroll
        for (int q = 0; q < 4; ++q) {
            float4 t = wq[q];
            wv[q*4+0]=t.x; wv[q*4+1]=t.y; wv[q*4+2]=t.z; wv[q*4+3]=t.w;
        }
        #pragma unroll
        for (int kx = 0; kx < 13; ++kx) {
            const float w = wv[kx];
            a0 = fmaf(w, rv[kx+0], a0);
            a1 = fmaf(w, rv[kx+1], a1);
            a2 = fmaf(w, rv[kx+2], a2);
            a3 = fmaf(w, rv[kx+3], a3);
        }
    }
}

__global__ __launch_bounds__(256) __attribute__((amdgpu_num_vgpr(168)))
void modeld_fused(const float* __restrict__ x,
                  const float* __restrict__ n_w1, const float* __restrict__ n_b1,
                  const float* __restrict__ n_w2, const float* __restrict__ n_b2,
                  const float* __restrict__ n_wl, const float* __restrict__ n_bl,
                  const float* __restrict__ c_w1, const float* __restrict__ c_b1,
                  const float* __restrict__ c_w2, const float* __restrict__ c_b2,
                  const float* __restrict__ c_wl, const float* __restrict__ c_bl,
                  float* __restrict__ out,
                  int* __restrict__ counter, int B)
{
    __shared__ SharedBufs sb;
    const int tid = threadIdx.x;
    const int dy  = tid / 7;          // dw/state mapping: thread<196 owns
    const int dx0 = (tid % 7) * 4;    // outputs (dy, dx0..dx0+3)

    // hoisted conv1 pad-correction constants (weights fixed for whole kernel)
    float nb=0.f, ne0=0.f, ne1=0.f, ne26=0.f, ne27=0.f;
    float cb=0.f, ce0=0.f, ce1=0.f, ce26=0.f, ce27=0.f;
    if (tid < 224) {
        conv1_corr(n_w1, n_b1, tid & 7, tid >> 3, nb, ne0, ne1, ne26, ne27);
        conv1_corr(c_w1, c_b1, tid & 7, tid >> 3, cb, ce0, ce1, ce26, ce27);
    }

    // one-time pad init for BOTH state buffers (pads persist; only interiors
    // are rewritten) and h1p zero pads.
    for (int i = tid; i < 2*40*RP40S; i += 256) sb.rp40[0][i] = -1.f;
    for (int i = tid; i < 8*28*H1W;   i += 256) sb.h1p[i]  = 0.f;

    while (true) {
        if (tid == 0) sb.next = atomicAdd(counter, 1);
        __syncthreads();                       // also orders pad init / prev sample
        const int b = sb.next;
        if (b >= B) break;                     // uniform exit

        // load x (float4 per dw mapping) into state buf 0; keep in regs
        float cur[4] = {0.f, 0.f, 0.f, 0.f};
        if (tid < 196) {
            const float4 t = *(const float4*)&x[b*784 + dy*28 + dx0];
            cur[0]=t.x; cur[1]=t.y; cur[2]=t.z; cur[3]=t.w;
            float* rp = &sb.rp40[0][(dy+6)*RP40S + dx0 + 6];
            rp[0]=t.x; rp[1]=t.y; rp[2]=t.z; rp[3]=t.w;
        }
        __syncthreads();

        // ---- n-trunk -> num[0..9]
        trunk_pass(sb, sb.rp40[0], tid, n_w1, n_w2, n_b2, nb, ne0, ne1, ne26, ne27);
        fc_tanh<10, false>(n_wl, n_bl, sb.pbuf, sb.num_s, tid);
        __syncthreads();

        float o[4];
        {
            const float n0 = sb.num_s[0];
            #pragma unroll
            for (int q = 0; q < 4; ++q) o[q] = n0 * cur[q];
        }

        // ---- 9 iterations, state ping-pongs between rp40[0] and rp40[1]
        int curbuf = 0;
        for (int k = 1; k <= 9; ++k) {
            const float* rpc = sb.rp40[curbuf];
            float*       rpn = sb.rp40[curbuf ^ 1];
            trunk_pass(sb, rpc, tid, c_w1, c_w2, c_b2, cb, ce0, ce1, ce26, ce27);
            fc_tanh<169, true>(c_wl, c_bl, sb.pbuf, sb.wker, tid);  // padded rows
            __syncthreads();
            if (tid < 196) {
                float a0, a1, a2, a3;
                depthwise13_regs(sb, rpc, dy, dx0, a0, a1, a2, a3);
                // write NEW state into the other buffer: no WAR hazard, no
                // extra barrier (dw reads rpc only; rpn is idle this iter)
                const float nk = sb.num_s[k];
                o[0] = fmaf(nk, a0, o[0]);
                o[1] = fmaf(nk, a1, o[1]);
                o[2] = fmaf(nk, a2, o[2]);
                o[3] = fmaf(nk, a3, o[3]);
                float* rp = &rpn[(dy+6)*RP40S + dx0 + 6];
                rp[0]=a0; rp[1]=a1; rp[2]=a2; rp[3]=a3;
            }
            __syncthreads();                   // new state visible to next conv1
            curbuf ^= 1;
        }

        if (tid < 196)
            *(float4*)&out[b*784 + dy*28 + dx0] = make_float4(o[0], o[1], o[2], o[3]);
        // no barrier needed: next iteration's grab+sync orders everything
    }
}

extern "C" void kernel_launch(void* const* d_in, const int* in_sizes, int n_in,
                              void* d_out, int out_size, void* d_ws, size_t ws_size,
                              hipStream_t stream)
{
    const float* x    = (const float*)d_in[0];
    const float* n_w1 = (const float*)d_in[1];
    const float* n_b1 = (const float*)d_in[2];
    const float* n_w2 = (const float*)d_in[3];
    const float* n_b2 = (const float*)d_in[4];
    const float* n_wl = (const float*)d_in[5];
    const float* n_bl = (const float*)d_in[6];
    const float* c_w1 = (const float*)d_in[7];
    const float* c_b1 = (const float*)d_in[8];
    const float* c_w2 = (const float*)d_in[9];
    const float* c_b2 = (const float*)d_in[10];
    const float* c_wl = (const float*)d_in[11];
    const float* c_bl = (const float*)d_in[12];
    float* out = (float*)d_out;

    const int B = in_sizes[0] / 784;
    hipMemsetAsync(d_ws, 0, sizeof(int), stream);   // work-stealing counter reset
    const int grid = B < 768 ? B : 768;             // 3 blocks/CU x 256 CUs
    hipLaunchKernelGGL(modeld_fused, dim3(grid), dim3(256), 0, stream,
                       x, n_w1, n_b1, n_w2, n_b2, n_wl, n_bl,
                       c_w1, c_b1, c_w2, c_b2, c_wl, c_bl, out,
                       (int*)d_ws, B);
}